// Round 1
// 419.227 us; speedup vs baseline: 1.0280x; 1.0280x over previous
//
#include <hip/hip_runtime.h>

typedef __bf16 bf16;
typedef __bf16 bf16x4 __attribute__((ext_vector_type(4)));
typedef __bf16 bf16x8 __attribute__((ext_vector_type(8)));
typedef float f32x4 __attribute__((ext_vector_type(4)));

#define NPIX 4096   // 64*64

// ---------------------------------------------------------------------------
// split_x: x[b][k][pix] fp32 -> 3 bf16 planes xT[b][pix][k] (h+m+l == x exact).
// grid = (16, 8, 8); block = 256
// ---------------------------------------------------------------------------
__global__ __launch_bounds__(256) void split_x(
    const float* __restrict__ x,   // [8][256][NPIX]
    bf16* __restrict__ xTh, bf16* __restrict__ xTm, bf16* __restrict__ xTl)
{
    const int pix = blockIdx.x * 256 + threadIdx.x;
    const int k0  = blockIdx.y * 32;
    const int b   = blockIdx.z;

    const float* __restrict__ src = x + ((size_t)b * 256 + k0) * NPIX + pix;
    float v[32];
#pragma unroll
    for (int kk = 0; kk < 32; ++kk) v[kk] = src[(size_t)kk * NPIX];

    const size_t drow = ((size_t)b * NPIX + pix) * 256 + k0;
#pragma unroll
    for (int c = 0; c < 4; ++c) {
        bf16x8 vh, vm, vl;
#pragma unroll
        for (int j = 0; j < 8; ++j) {
            float val = v[c * 8 + j];
            bf16 h = (bf16)val; float r  = val - (float)h;
            bf16 m = (bf16)r;   float r2 = r - (float)m;
            vh[j] = h; vm[j] = m; vl[j] = (bf16)r2;
        }
        *(bf16x8*)(xTh + drow + c * 8) = vh;
        *(bf16x8*)(xTm + drow + c * 8) = vm;
        *(bf16x8*)(xTl + drow + c * 8) = vl;
    }
}

// ---------------------------------------------------------------------------
// split_w3: w[i] fp32 -> 3 bf16 planes (h+m+l == w exact). n = grid*256 exact.
// ---------------------------------------------------------------------------
__global__ __launch_bounds__(256) void split_w3(
    const float* __restrict__ w,
    bf16* __restrict__ h, bf16* __restrict__ m, bf16* __restrict__ l)
{
    const int i = blockIdx.x * 256 + threadIdx.x;
    const float v = w[i];
    const bf16 a = (bf16)v;  const float r1 = v - (float)a;
    const bf16 c = (bf16)r1;
    h[i] = a; m[i] = c; l[i] = (bf16)(r1 - (float)c);
}

// split_w2: w[i] fp32 -> 2 bf16 planes.
__global__ __launch_bounds__(256) void split_w2(
    const float* __restrict__ w, bf16* __restrict__ h, bf16* __restrict__ m)
{
    const int i = blockIdx.x * 256 + threadIdx.x;
    const float v = w[i];
    const bf16 a = (bf16)v;
    h[i] = a; m[i] = (bf16)(v - (float)a);
}

// ---------------------------------------------------------------------------
// qkv GEMM via split-3 bf16 MFMA (6 products == fp32-accurate).
// v2: pre-split A planes, global_load_lds double-buffered staging,
//     ONE raw barrier per K-step, no in-loop conversion / ds_write.
// grid = (32, 6, 8); block = 256
// ---------------------------------------------------------------------------
__global__ __launch_bounds__(256, 2) void qkv_mfma(
    const bf16* __restrict__ Ah, const bf16* __restrict__ Am,
    const bf16* __restrict__ Al,                     // [768][256] bf16 planes
    const bf16* __restrict__ xTh, const bf16* __restrict__ xTm,
    const bf16* __restrict__ xTl,                    // [8][NPIX][256]
    float* __restrict__ C)                           // [8][768][NPIX]
{
    __shared__ __align__(16) bf16 As[2][3][128][32];   // 48 KiB, linear rows

    const int tid  = threadIdx.x;
    const int lane = tid & 63;
    const int wv   = tid >> 6;
    const int col  = lane & 15;
    const int quad = lane >> 4;
    const int wm   = (wv >> 1) * 64;
    const int wn   = (wv & 1) * 64;
    const int n0   = blockIdx.x * 128;
    const int m0   = blockIdx.y * 128;
    const int b    = blockIdx.z;

    const size_t xoff = ((size_t)b * NPIX + n0 + wn) * 256;

    // staging geometry: each issue moves 4 KiB (256 lanes x 16 B); wave-linear.
    const int srow = wv * 16 + (lane >> 2);   // row within 64-row half
    const int schk = (lane & 3) * 8;          // 8-elem chunk within row

    const bf16* AP[3] = {Ah, Am, Al};

    auto stage = [&](int buf, int kk) {
#pragma unroll
        for (int p = 0; p < 3; ++p)
#pragma unroll
            for (int hh = 0; hh < 2; ++hh) {
                const bf16* gp = AP[p] + (size_t)(m0 + hh * 64 + srow) * 256 + kk + schk;
                __builtin_amdgcn_global_load_lds(
                    (const __attribute__((address_space(1))) void*)gp,
                    (__attribute__((address_space(3))) void*)&As[buf][p][hh * 64 + wv * 16][0],
                    16, 0, 0);
            }
    };

    f32x4 acc[4][4] = {};

    stage(0, 0);   // prologue

#pragma unroll
    for (int k0 = 0; k0 < 256; k0 += 32) {
        const int cur = (k0 >> 5) & 1;

        asm volatile("s_waitcnt vmcnt(0)" ::: "memory");   // prefetch landed
        __builtin_amdgcn_s_barrier();                      // all waves' too
        __builtin_amdgcn_sched_barrier(0);

        // LDS -> A fragments (consumed by MFMAs before next barrier)
        bf16x8 af[4][3];
#pragma unroll
        for (int s = 0; s < 4; ++s)
#pragma unroll
            for (int p = 0; p < 3; ++p)
                af[s][p] = *(const bf16x8*)&As[cur][p][wm + s * 16 + col][quad * 8];

        // issue next A tile (lands by next iter's vmcnt(0))
        if (k0 + 32 < 256) stage(cur ^ 1, k0 + 32);

        // B fragments straight from global (L2/L3-resident), group order
        bf16x8 bh[4], bl[4], bm[4];
#pragma unroll
        for (int t = 0; t < 4; ++t) {
            const size_t brow = xoff + (size_t)(t * 16 + col) * 256 + k0 + quad * 8;
            bh[t] = *(const bf16x8*)(xTh + brow);
        }
#pragma unroll
        for (int t = 0; t < 4; ++t) {
            const size_t brow = xoff + (size_t)(t * 16 + col) * 256 + k0 + quad * 8;
            bl[t] = *(const bf16x8*)(xTl + brow);
        }
#pragma unroll
        for (int t = 0; t < 4; ++t) {
            const size_t brow = xoff + (size_t)(t * 16 + col) * 256 + k0 + quad * 8;
            bm[t] = *(const bf16x8*)(xTm + brow);
        }

#pragma unroll
        for (int t = 0; t < 4; ++t)
#pragma unroll
            for (int s = 0; s < 4; ++s)
                acc[s][t] = __builtin_amdgcn_mfma_f32_16x16x32_bf16(af[s][2], bh[t], acc[s][t], 0, 0, 0);
#pragma unroll
        for (int t = 0; t < 4; ++t)
#pragma unroll
            for (int s = 0; s < 4; ++s)
                acc[s][t] = __builtin_amdgcn_mfma_f32_16x16x32_bf16(af[s][0], bl[t], acc[s][t], 0, 0, 0);
#pragma unroll
        for (int t = 0; t < 4; ++t)
#pragma unroll
            for (int s = 0; s < 4; ++s)
                acc[s][t] = __builtin_amdgcn_mfma_f32_16x16x32_bf16(af[s][1], bm[t], acc[s][t], 0, 0, 0);
#pragma unroll
        for (int t = 0; t < 4; ++t)
#pragma unroll
            for (int s = 0; s < 4; ++s)
                acc[s][t] = __builtin_amdgcn_mfma_f32_16x16x32_bf16(af[s][1], bh[t], acc[s][t], 0, 0, 0);
#pragma unroll
        for (int t = 0; t < 4; ++t)
#pragma unroll
            for (int s = 0; s < 4; ++s)
                acc[s][t] = __builtin_amdgcn_mfma_f32_16x16x32_bf16(af[s][0], bm[t], acc[s][t], 0, 0, 0);
#pragma unroll
        for (int t = 0; t < 4; ++t)
#pragma unroll
            for (int s = 0; s < 4; ++s)
                acc[s][t] = __builtin_amdgcn_mfma_f32_16x16x32_bf16(af[s][0], bh[t], acc[s][t], 0, 0, 0);
    }

    float* __restrict__ Cp = C + (size_t)b * 768 * NPIX;
#pragma unroll
    for (int s = 0; s < 4; ++s)
#pragma unroll
        for (int t = 0; t < 4; ++t)
#pragma unroll
            for (int r = 0; r < 4; ++r) {
                const int m = m0 + wm + s * 16 + quad * 4 + r;
                const int n = n0 + wn + t * 16 + col;
                Cp[(size_t)m * NPIX + n] = acc[s][t][r];
            }
}

// ---------------------------------------------------------------------------
// Fused depthwise 5x5 (pad 2) + grouped pointwise 8->8. Unchanged.
// grid = (4, 96, 8); block = 256
// ---------------------------------------------------------------------------
__global__ __launch_bounds__(256) void dwpw(
    const float* __restrict__ qkv,   // [batch][768][NPIX]
    const float* __restrict__ w_dw,  // [768][25]
    const float* __restrict__ w_pw,  // [768][8]
    float* __restrict__ agg)         // [batch][768][NPIX]
{
    __shared__ float sm[8][20][72];  // data cols 4..67; halo cols 2,3,68,69

    const int tid = threadIdx.x;
    const int y0  = blockIdx.x * 16;
    const int p   = blockIdx.y;
    const int b   = blockIdx.z;

    const float* __restrict__ src = qkv + ((size_t)b * 768 + 8 * p) * NPIX;

#pragma unroll
    for (int it = 0; it < 10; ++it) {
        int idx = tid + it * 256;
        int c  = idx / 320;
        int r  = idx % 320;
        int sy = r >> 4;
        int x4 = (r & 15) * 4;
        int gy = y0 + sy - 2;
        float4 v = {0.f, 0.f, 0.f, 0.f};
        if ((unsigned)gy < 64u)
            v = *(const float4*)(src + (size_t)c * NPIX + gy * 64 + x4);
        *(float4*)&sm[c][sy][4 + x4] = v;
    }
    if (tid < 160) {
        int c = tid / 20, sy = tid % 20;
        sm[c][sy][2] = 0.f; sm[c][sy][3] = 0.f;
        sm[c][sy][68] = 0.f; sm[c][sy][69] = 0.f;
    }
    __syncthreads();

    const int ty = tid >> 4;
    const int x0 = (tid & 15) * 4;

    float d[8][4];
#pragma unroll
    for (int c = 0; c < 8; ++c) {
        float a0 = 0.f, a1 = 0.f, a2 = 0.f, a3 = 0.f;
        const float* __restrict__ wc = w_dw + (size_t)(8 * p + c) * 25;
#pragma unroll
        for (int ky = 0; ky < 5; ++ky) {
            float r[12];
            *(float4*)&r[0] = *(const float4*)&sm[c][ty + ky][x0];
            *(float4*)&r[4] = *(const float4*)&sm[c][ty + ky][x0 + 4];
            *(float4*)&r[8] = *(const float4*)&sm[c][ty + ky][x0 + 8];
#pragma unroll
            for (int kx = 0; kx < 5; ++kx) {
                const float wv = wc[ky * 5 + kx];
                a0 = fmaf(wv, r[2 + 0 + kx], a0);
                a1 = fmaf(wv, r[2 + 1 + kx], a1);
                a2 = fmaf(wv, r[2 + 2 + kx], a2);
                a3 = fmaf(wv, r[2 + 3 + kx], a3);
            }
        }
        d[c][0] = a0; d[c][1] = a1; d[c][2] = a2; d[c][3] = a3;
    }

    float* __restrict__ dst = agg + ((size_t)b * 768 + 8 * p) * NPIX + (y0 + ty) * 64 + x0;
#pragma unroll
    for (int o = 0; o < 8; ++o) {
        const float* __restrict__ wo = w_pw + (size_t)(8 * p + o) * 8;
        float4 s = {0.f, 0.f, 0.f, 0.f};
#pragma unroll
        for (int i = 0; i < 8; ++i) {
            const float wv = wo[i];
            s.x = fmaf(wv, d[i][0], s.x);
            s.y = fmaf(wv, d[i][1], s.y);
            s.z = fmaf(wv, d[i][2], s.z);
            s.w = fmaf(wv, d[i][3], s.w);
        }
        *(float4*)(dst + (size_t)o * NPIX) = s;
    }
}

// ---------------------------------------------------------------------------
// kv reduction. Unchanged. grid = (64, batch); block = 256
// ---------------------------------------------------------------------------
__global__ __launch_bounds__(256) void kv_reduce(
    const float* __restrict__ qkv, const float* __restrict__ agg,
    float* __restrict__ kvb)      // [batch][64][72]
{
    const int g = blockIdx.x, b = blockIdx.y;
    const float* __restrict__ src = (g < 32) ? qkv : agg;
    const float* __restrict__ base = src + ((size_t)b * 768 + 24 * (g & 31)) * NPIX;

    float acc[72];
#pragma unroll
    for (int i = 0; i < 72; ++i) acc[i] = 0.0f;

    for (int i4 = threadIdx.x; i4 < NPIX / 4; i4 += 256) {
        float4 kf[8], vf[8];
#pragma unroll
        for (int d = 0; d < 8; ++d) {
            float4 t = ((const float4*)(base + (size_t)(8 + d) * NPIX))[i4];
            kf[d].x = fmaxf(0.0f, t.x); kf[d].y = fmaxf(0.0f, t.y);
            kf[d].z = fmaxf(0.0f, t.z); kf[d].w = fmaxf(0.0f, t.w);
        }
#pragma unroll
        for (int e = 0; e < 8; ++e)
            vf[e] = ((const float4*)(base + (size_t)(16 + e) * NPIX))[i4];
#pragma unroll
        for (int d = 0; d < 8; ++d) {
#pragma unroll
            for (int e = 0; e < 8; ++e)
                acc[d * 9 + e] += kf[d].x * vf[e].x + kf[d].y * vf[e].y +
                                  kf[d].z * vf[e].z + kf[d].w * vf[e].w;
            acc[d * 9 + 8] += kf[d].x + kf[d].y + kf[d].z + kf[d].w;
        }
    }

    const int lane = threadIdx.x & 63;
    const int wv   = threadIdx.x >> 6;
#pragma unroll
    for (int i = 0; i < 72; ++i) {
        float v = acc[i];
        v += __shfl_xor(v, 32, 64);
        v += __shfl_xor(v, 16, 64);
        v += __shfl_xor(v, 8, 64);
        v += __shfl_xor(v, 4, 64);
        v += __shfl_xor(v, 2, 64);
        v += __shfl_xor(v, 1, 64);
        acc[i] = v;
    }
    __shared__ float red[4][72];
    if (lane == 0) {
#pragma unroll
        for (int i = 0; i < 72; ++i) red[wv][i] = acc[i];
    }
    __syncthreads();
    if (threadIdx.x < 72)
        kvb[((size_t)b * 64 + g) * 72 + threadIdx.x] =
            red[0][threadIdx.x] + red[1][threadIdx.x] +
            red[2][threadIdx.x] + red[3][threadIdx.x];
}

// ---------------------------------------------------------------------------
// attn_fused. Unchanged. grid = (128, 8); block = 256
// ---------------------------------------------------------------------------
__global__ __launch_bounds__(256) void attn_fused(
    const float* __restrict__ qkv, const float* __restrict__ agg,
    const float* __restrict__ kvb,   // [batch][64][72]
    bf16* __restrict__ attTh, bf16* __restrict__ attTm)  // [8][NPIX][512]
{
    const int b   = blockIdx.y;
    const int n0  = blockIdx.x * 32;
    const int tid = threadIdx.x;
    const int p   = tid & 31;
    const int c   = tid >> 5;

    __shared__ float kvs[64 * 72];
    for (int i = tid; i < 64 * 72; i += 256) kvs[i] = kvb[(size_t)b * 64 * 72 + i];
    __syncthreads();

    const int n = n0 + p;
    const size_t orow = ((size_t)b * NPIX + n) * 512;

#pragma unroll
    for (int gi = 0; gi < 8; ++gi) {
        const int g = c * 8 + gi;
        const float* __restrict__ src = (g < 32) ? qkv : agg;
        const float* __restrict__ base = src + ((size_t)b * 768 + 24 * (g & 31)) * NPIX + n;

        float q[8];
#pragma unroll
        for (int d = 0; d < 8; ++d) q[d] = fmaxf(0.0f, base[(size_t)d * NPIX]);

        const float* kv = &kvs[g * 72];
        float den = 1e-15f;
#pragma unroll
        for (int d = 0; d < 8; ++d) den = fmaf(q[d], kv[d * 9 + 8], den);
        float inv = 1.0f / den;
#pragma unroll
        for (int d = 0; d < 8; ++d) q[d] *= inv;

        bf16x8 vh, vm;
#pragma unroll
        for (int e = 0; e < 8; ++e) {
            float o = 0.0f;
#pragma unroll
            for (int d = 0; d < 8; ++d) o = fmaf(q[d], kv[d * 9 + e], o);
            bf16 h = (bf16)o;
            vh[e] = h;
            vm[e] = (bf16)(o - (float)h);
        }
        *(bf16x8*)(attTh + orow + g * 8) = vh;
        *(bf16x8*)(attTm + orow + g * 8) = vm;
    }
}

// ---------------------------------------------------------------------------
// proj GEMM via split-2 bf16 MFMA + fused BN.
// v2: pre-split A planes + global_load_lds staging, one barrier per K-step.
// grid = (32, 2, 8); block = 256
// ---------------------------------------------------------------------------
__global__ __launch_bounds__(256, 2) void proj_mfma(
    const bf16* __restrict__ Ph, const bf16* __restrict__ Pm,  // [256][512]
    const bf16* __restrict__ Bh, const bf16* __restrict__ Bm,  // [8][NPIX][512]
    float* __restrict__ C,           // [8][256][NPIX]
    const float* __restrict__ bn_g, const float* __restrict__ bn_b,
    const float* __restrict__ bn_m, const float* __restrict__ bn_v)
{
    __shared__ __align__(16) bf16 As[2][2][128][32];   // 32 KiB

    const int tid  = threadIdx.x;
    const int lane = tid & 63;
    const int wv   = tid >> 6;
    const int col  = lane & 15;
    const int quad = lane >> 4;
    const int wm   = (wv >> 1) * 64;
    const int wn   = (wv & 1) * 64;
    const int n0   = blockIdx.x * 128;
    const int m0   = blockIdx.y * 128;
    const int b    = blockIdx.z;

    const size_t boff = ((size_t)b * NPIX + n0 + wn) * 512;

    const int srow = wv * 16 + (lane >> 2);
    const int schk = (lane & 3) * 8;

    const bf16* AP[2] = {Ph, Pm};

    auto stage = [&](int buf, int kk) {
#pragma unroll
        for (int p = 0; p < 2; ++p)
#pragma unroll
            for (int hh = 0; hh < 2; ++hh) {
                const bf16* gp = AP[p] + (size_t)(m0 + hh * 64 + srow) * 512 + kk + schk;
                __builtin_amdgcn_global_load_lds(
                    (const __attribute__((address_space(1))) void*)gp,
                    (__attribute__((address_space(3))) void*)&As[buf][p][hh * 64 + wv * 16][0],
                    16, 0, 0);
            }
    };

    f32x4 acc[4][4] = {};

    stage(0, 0);

#pragma unroll
    for (int k0 = 0; k0 < 512; k0 += 32) {
        const int cur = (k0 >> 5) & 1;

        asm volatile("s_waitcnt vmcnt(0)" ::: "memory");
        __builtin_amdgcn_s_barrier();
        __builtin_amdgcn_sched_barrier(0);

        bf16x8 af0[4], af1[4];
#pragma unroll
        for (int s = 0; s < 4; ++s) {
            af0[s] = *(const bf16x8*)&As[cur][0][wm + s * 16 + col][quad * 8];
            af1[s] = *(const bf16x8*)&As[cur][1][wm + s * 16 + col][quad * 8];
        }

        if (k0 + 32 < 512) stage(cur ^ 1, k0 + 32);

        bf16x8 bh[4], bm2[4];
#pragma unroll
        for (int t = 0; t < 4; ++t) {
            const size_t brow = boff + (size_t)(t * 16 + col) * 512 + k0 + quad * 8;
            bh[t] = *(const bf16x8*)(Bh + brow);
        }
#pragma unroll
        for (int t = 0; t < 4; ++t) {
            const size_t brow = boff + (size_t)(t * 16 + col) * 512 + k0 + quad * 8;
            bm2[t] = *(const bf16x8*)(Bm + brow);
        }

#pragma unroll
        for (int t = 0; t < 4; ++t)
#pragma unroll
            for (int s = 0; s < 4; ++s)
                acc[s][t] = __builtin_amdgcn_mfma_f32_16x16x32_bf16(af1[s], bh[t], acc[s][t], 0, 0, 0);
#pragma unroll
        for (int t = 0; t < 4; ++t)
#pragma unroll
            for (int s = 0; s < 4; ++s)
                acc[s][t] = __builtin_amdgcn_mfma_f32_16x16x32_bf16(af0[s], bm2[t], acc[s][t], 0, 0, 0);
#pragma unroll
        for (int t = 0; t < 4; ++t)
#pragma unroll
            for (int s = 0; s < 4; ++s)
                acc[s][t] = __builtin_amdgcn_mfma_f32_16x16x32_bf16(af0[s], bh[t], acc[s][t], 0, 0, 0);
    }

    float* __restrict__ Cp = C + (size_t)b * 256 * NPIX;
#pragma unroll
    for (int s = 0; s < 4; ++s) {
#pragma unroll
        for (int r = 0; r < 4; ++r) {
            const int m = m0 + wm + s * 16 + quad * 4 + r;
            const float sc  = (1.0f / sqrtf(bn_v[m] + 1e-5f)) * bn_g[m];
            const float off = bn_b[m] - bn_m[m] * sc;
#pragma unroll
            for (int t = 0; t < 4; ++t) {
                const int n = n0 + wn + t * 16 + col;
                Cp[(size_t)m * NPIX + n] = acc[s][t][r] * sc + off;
            }
        }
    }
}

// ---------------------------------------------------------------------------
extern "C" void kernel_launch(void* const* d_in, const int* in_sizes, int n_in,
                              void* d_out, int out_size, void* d_ws, size_t ws_size,
                              hipStream_t stream) {
    const float* x      = (const float*)d_in[0];
    const float* w_qkv  = (const float*)d_in[1];
    const float* w_dw   = (const float*)d_in[2];
    const float* w_pw   = (const float*)d_in[3];
    const float* w_proj = (const float*)d_in[4];
    const float* bn_g   = (const float*)d_in[5];
    const float* bn_b   = (const float*)d_in[6];
    const float* bn_m   = (const float*)d_in[7];
    const float* bn_v   = (const float*)d_in[8];
    float* out = (float*)d_out;

    // ws: qkv 96 MiB + agg 96 MiB + region3 64 MiB = 256 MiB.
    // region3: xT planes (48 MiB) + wq planes (1.2 MiB at +48Mi) until
    //          qkv_mfma done, then attT h+m (2 x 32 MiB) overwrite it.
    // wp planes (0.5 MiB) go into the qkv region AFTER attn_fused (qkv dead).
    // kvb (147 KB) lives in d_out; proj_mfma overwrites all of d_out last.
    char* ws = (char*)d_ws;
    float* qkv  = (float*)ws;                        // 100663296 B
    float* agg  = (float*)(ws + 100663296ull);       // 100663296 B
    char*  r3   = ws + 201326592ull;                 // 67108864 B
    bf16*  xTh  = (bf16*)r3;                         // 16777216 B
    bf16*  xTm  = (bf16*)(r3 + 16777216ull);         // 16777216 B
    bf16*  xTl  = (bf16*)(r3 + 33554432ull);         // 16777216 B
    bf16*  wqh  = (bf16*)(r3 + 50331648ull);         // 393216 B
    bf16*  wqm  = (bf16*)(r3 + 50331648ull + 393216ull);
    bf16*  wql  = (bf16*)(r3 + 50331648ull + 786432ull);
    bf16*  attTh = (bf16*)r3;                        // 33554432 B
    bf16*  attTm = (bf16*)(r3 + 33554432ull);        // 33554432 B
    bf16*  wph  = (bf16*)ws;                         // 262144 B (qkv dead)
    bf16*  wpm  = (bf16*)(ws + 262144ull);           // 262144 B
    float* kvb  = (float*)d_out;

    // 0) split + transpose x into 3 bf16 planes (h+m+l == x exactly)
    split_x<<<dim3(16, 8, 8), dim3(256), 0, stream>>>(x, xTh, xTm, xTl);

    // 0b) split w_qkv into 3 bf16 planes (768*256 = 196608 = 768*256 threads)
    split_w3<<<dim3(768), dim3(256), 0, stream>>>(w_qkv, wqh, wqm, wql);

    // 1) qkv = w_qkv @ x  (split-3 MFMA, fp32-accurate)
    qkv_mfma<<<dim3(32, 6, 8), dim3(256), 0, stream>>>(
        wqh, wqm, wql, xTh, xTm, xTl, qkv);

    // 2) agg = grouped-pw( depthwise-5x5( qkv ) )
    dwpw<<<dim3(4, 96, 8), dim3(256), 0, stream>>>(qkv, w_dw, w_pw, agg);

    // 3) kv reduction per (g, b)
    kv_reduce<<<dim3(64, 8), dim3(256), 0, stream>>>(qkv, agg, kvb);

    // 4) attention -> transposed split-2 bf16 attT (xT + wq region now dead)
    attn_fused<<<dim3(128, 8), dim3(256), 0, stream>>>(qkv, agg, kvb, attTh, attTm);

    // 4b) split w_proj into 2 bf16 planes (256*512 = 131072 = 512*256 threads)
    //     -> qkv region (dead after attn_fused)
    split_w2<<<dim3(512), dim3(256), 0, stream>>>(w_proj, wph, wpm);

    // 5) out = BN( w_proj @ att )  (split-2 MFMA; overwrites all of d_out)
    proj_mfma<<<dim3(32, 2, 8), dim3(256), 0, stream>>>(
        wph, wpm, attTh, attTm, out, bn_g, bn_b, bn_m, bn_v);
}

// Round 3
// 414.321 us; speedup vs baseline: 1.0402x; 1.0118x over previous
//
#include <hip/hip_runtime.h>

typedef __bf16 bf16;
typedef __bf16 bf16x4 __attribute__((ext_vector_type(4)));
typedef __bf16 bf16x8 __attribute__((ext_vector_type(8)));
typedef float f32x4 __attribute__((ext_vector_type(4)));

#define NPIX 4096   // 64*64

// ---------------------------------------------------------------------------
// split_x: x[b][k][pix] fp32 -> 3 bf16 planes xT[b][pix][k] (h+m+l == x exact).
// grid = (16, 8, 8); block = 256
// ---------------------------------------------------------------------------
__global__ __launch_bounds__(256) void split_x(
    const float* __restrict__ x,   // [8][256][NPIX]
    bf16* __restrict__ xTh, bf16* __restrict__ xTm, bf16* __restrict__ xTl)
{
    const int pix = blockIdx.x * 256 + threadIdx.x;
    const int k0  = blockIdx.y * 32;
    const int b   = blockIdx.z;

    const float* __restrict__ src = x + ((size_t)b * 256 + k0) * NPIX + pix;
    float v[32];
#pragma unroll
    for (int kk = 0; kk < 32; ++kk) v[kk] = src[(size_t)kk * NPIX];

    const size_t drow = ((size_t)b * NPIX + pix) * 256 + k0;
#pragma unroll
    for (int c = 0; c < 4; ++c) {
        bf16x8 vh, vm, vl;
#pragma unroll
        for (int j = 0; j < 8; ++j) {
            float val = v[c * 8 + j];
            bf16 h = (bf16)val; float r  = val - (float)h;
            bf16 m = (bf16)r;   float r2 = r - (float)m;
            vh[j] = h; vm[j] = m; vl[j] = (bf16)r2;
        }
        *(bf16x8*)(xTh + drow + c * 8) = vh;
        *(bf16x8*)(xTm + drow + c * 8) = vm;
        *(bf16x8*)(xTl + drow + c * 8) = vl;
    }
}

// ---------------------------------------------------------------------------
// split_w3: w[i] fp32 -> 3 bf16 planes (h+m+l == w exact). n = grid*256 exact.
// ---------------------------------------------------------------------------
__global__ __launch_bounds__(256) void split_w3(
    const float* __restrict__ w,
    bf16* __restrict__ h, bf16* __restrict__ m, bf16* __restrict__ l)
{
    const int i = blockIdx.x * 256 + threadIdx.x;
    const float v = w[i];
    const bf16 a = (bf16)v;  const float r1 = v - (float)a;
    const bf16 c = (bf16)r1;
    h[i] = a; m[i] = c; l[i] = (bf16)(r1 - (float)c);
}

// split_w2: w[i] fp32 -> 2 bf16 planes.
__global__ __launch_bounds__(256) void split_w2(
    const float* __restrict__ w, bf16* __restrict__ h, bf16* __restrict__ m)
{
    const int i = blockIdx.x * 256 + threadIdx.x;
    const float v = w[i];
    const bf16 a = (bf16)v;
    h[i] = a; m[i] = (bf16)(v - (float)a);
}

// ---------------------------------------------------------------------------
// qkv GEMM via split-3 bf16 MFMA (6 products == fp32-accurate).
// v4: B fragments software-pipelined one K-step ahead in registers;
//     plain __syncthreads() per K-step (compiler-managed waitcnt drain).
//     No inline asm. Prefetched loads have the full MFMA section to land.
// grid = (32, 6, 8); block = 256
// ---------------------------------------------------------------------------
__global__ __launch_bounds__(256, 2) void qkv_mfma(
    const bf16* __restrict__ Ah, const bf16* __restrict__ Am,
    const bf16* __restrict__ Al,                     // [768][256] bf16 planes
    const bf16* __restrict__ xTh, const bf16* __restrict__ xTm,
    const bf16* __restrict__ xTl,                    // [8][NPIX][256]
    float* __restrict__ C)                           // [8][768][NPIX]
{
    __shared__ __align__(16) bf16 As[2][3][128][32];   // 48 KiB, linear rows

    const int tid  = threadIdx.x;
    const int lane = tid & 63;
    const int wv   = tid >> 6;
    const int col  = lane & 15;
    const int quad = lane >> 4;
    const int wm   = (wv >> 1) * 64;
    const int wn   = (wv & 1) * 64;
    const int n0   = blockIdx.x * 128;
    const int m0   = blockIdx.y * 128;
    const int b    = blockIdx.z;

    const size_t xoff = ((size_t)b * NPIX + n0 + wn) * 256;

    // staging geometry: each issue moves 4 KiB (256 lanes x 16 B); wave-linear.
    const int srow = wv * 16 + (lane >> 2);   // row within 64-row half
    const int schk = (lane & 3) * 8;          // 8-elem chunk within row

    const bf16* AP[3] = {Ah, Am, Al};

    auto stage = [&](int buf, int kk) {
#pragma unroll
        for (int p = 0; p < 3; ++p)
#pragma unroll
            for (int hh = 0; hh < 2; ++hh) {
                const bf16* gp = AP[p] + (size_t)(m0 + hh * 64 + srow) * 256 + kk + schk;
                __builtin_amdgcn_global_load_lds(
                    (const __attribute__((address_space(1))) void*)gp,
                    (__attribute__((address_space(3))) void*)&As[buf][p][hh * 64 + wv * 16][0],
                    16, 0, 0);
            }
    };

    f32x4 acc[4][4] = {};

    // prologue: A tile 0 (6 loads), then B fragments for k0=0 (12 loads)
    stage(0, 0);
    bf16x8 bh[4], bl[4], bm[4];
#pragma unroll
    for (int t = 0; t < 4; ++t) {
        const size_t brow = xoff + (size_t)(t * 16 + col) * 256 + 0 + quad * 8;
        bh[t] = *(const bf16x8*)(xTh + brow);
        bl[t] = *(const bf16x8*)(xTl + brow);
        bm[t] = *(const bf16x8*)(xTm + brow);
    }

#pragma unroll
    for (int k0 = 0; k0 < 256; k0 += 32) {
        const int cur = (k0 >> 5) & 1;
        const bool more = (k0 + 32 < 256);

        // drain (vmcnt(0)+lgkmcnt(0)) + barrier: A(i) in LDS, B(i) in regs.
        // Loads being drained were issued before last iteration's MFMA block.
        __syncthreads();

        // LDS -> A fragments
        bf16x8 af[4][3];
#pragma unroll
        for (int s = 0; s < 4; ++s)
#pragma unroll
            for (int p = 0; p < 3; ++p)
                af[s][p] = *(const bf16x8*)&As[cur][p][wm + s * 16 + col][quad * 8];

        // issue next A tile (6 global_load_lds) + next B fragments (12 loads);
        // they land during this step's MFMA section.
        bf16x8 nbh[4], nbl[4], nbm[4];
        if (more) {
            stage(cur ^ 1, k0 + 32);
#pragma unroll
            for (int t = 0; t < 4; ++t) {
                const size_t brow = xoff + (size_t)(t * 16 + col) * 256 + (k0 + 32) + quad * 8;
                nbh[t] = *(const bf16x8*)(xTh + brow);
                nbl[t] = *(const bf16x8*)(xTl + brow);
                nbm[t] = *(const bf16x8*)(xTm + brow);
            }
        }

#pragma unroll
        for (int t = 0; t < 4; ++t)
#pragma unroll
            for (int s = 0; s < 4; ++s)
                acc[s][t] = __builtin_amdgcn_mfma_f32_16x16x32_bf16(af[s][2], bh[t], acc[s][t], 0, 0, 0);
#pragma unroll
        for (int t = 0; t < 4; ++t)
#pragma unroll
            for (int s = 0; s < 4; ++s)
                acc[s][t] = __builtin_amdgcn_mfma_f32_16x16x32_bf16(af[s][0], bl[t], acc[s][t], 0, 0, 0);
#pragma unroll
        for (int t = 0; t < 4; ++t)
#pragma unroll
            for (int s = 0; s < 4; ++s)
                acc[s][t] = __builtin_amdgcn_mfma_f32_16x16x32_bf16(af[s][1], bm[t], acc[s][t], 0, 0, 0);
#pragma unroll
        for (int t = 0; t < 4; ++t)
#pragma unroll
            for (int s = 0; s < 4; ++s)
                acc[s][t] = __builtin_amdgcn_mfma_f32_16x16x32_bf16(af[s][1], bh[t], acc[s][t], 0, 0, 0);
#pragma unroll
        for (int t = 0; t < 4; ++t)
#pragma unroll
            for (int s = 0; s < 4; ++s)
                acc[s][t] = __builtin_amdgcn_mfma_f32_16x16x32_bf16(af[s][0], bm[t], acc[s][t], 0, 0, 0);
#pragma unroll
        for (int t = 0; t < 4; ++t)
#pragma unroll
            for (int s = 0; s < 4; ++s)
                acc[s][t] = __builtin_amdgcn_mfma_f32_16x16x32_bf16(af[s][0], bh[t], acc[s][t], 0, 0, 0);

        // rotate prefetched B into current (unrolled -> pure renaming)
        if (more) {
#pragma unroll
            for (int t = 0; t < 4; ++t) {
                bh[t] = nbh[t]; bl[t] = nbl[t]; bm[t] = nbm[t];
            }
        }
    }

    float* __restrict__ Cp = C + (size_t)b * 768 * NPIX;
#pragma unroll
    for (int s = 0; s < 4; ++s)
#pragma unroll
        for (int t = 0; t < 4; ++t)
#pragma unroll
            for (int r = 0; r < 4; ++r) {
                const int m = m0 + wm + s * 16 + quad * 4 + r;
                const int n = n0 + wn + t * 16 + col;
                Cp[(size_t)m * NPIX + n] = acc[s][t][r];
            }
}

// ---------------------------------------------------------------------------
// Fused depthwise 5x5 (pad 2) + grouped pointwise 8->8. Unchanged.
// grid = (4, 96, 8); block = 256
// ---------------------------------------------------------------------------
__global__ __launch_bounds__(256) void dwpw(
    const float* __restrict__ qkv,   // [batch][768][NPIX]
    const float* __restrict__ w_dw,  // [768][25]
    const float* __restrict__ w_pw,  // [768][8]
    float* __restrict__ agg)         // [batch][768][NPIX]
{
    __shared__ float sm[8][20][72];  // data cols 4..67; halo cols 2,3,68,69

    const int tid = threadIdx.x;
    const int y0  = blockIdx.x * 16;
    const int p   = blockIdx.y;
    const int b   = blockIdx.z;

    const float* __restrict__ src = qkv + ((size_t)b * 768 + 8 * p) * NPIX;

#pragma unroll
    for (int it = 0; it < 10; ++it) {
        int idx = tid + it * 256;
        int c  = idx / 320;
        int r  = idx % 320;
        int sy = r >> 4;
        int x4 = (r & 15) * 4;
        int gy = y0 + sy - 2;
        float4 v = {0.f, 0.f, 0.f, 0.f};
        if ((unsigned)gy < 64u)
            v = *(const float4*)(src + (size_t)c * NPIX + gy * 64 + x4);
        *(float4*)&sm[c][sy][4 + x4] = v;
    }
    if (tid < 160) {
        int c = tid / 20, sy = tid % 20;
        sm[c][sy][2] = 0.f; sm[c][sy][3] = 0.f;
        sm[c][sy][68] = 0.f; sm[c][sy][69] = 0.f;
    }
    __syncthreads();

    const int ty = tid >> 4;
    const int x0 = (tid & 15) * 4;

    float d[8][4];
#pragma unroll
    for (int c = 0; c < 8; ++c) {
        float a0 = 0.f, a1 = 0.f, a2 = 0.f, a3 = 0.f;
        const float* __restrict__ wc = w_dw + (size_t)(8 * p + c) * 25;
#pragma unroll
        for (int ky = 0; ky < 5; ++ky) {
            float r[12];
            *(float4*)&r[0] = *(const float4*)&sm[c][ty + ky][x0];
            *(float4*)&r[4] = *(const float4*)&sm[c][ty + ky][x0 + 4];
            *(float4*)&r[8] = *(const float4*)&sm[c][ty + ky][x0 + 8];
#pragma unroll
            for (int kx = 0; kx < 5; ++kx) {
                const float wv = wc[ky * 5 + kx];
                a0 = fmaf(wv, r[2 + 0 + kx], a0);
                a1 = fmaf(wv, r[2 + 1 + kx], a1);
                a2 = fmaf(wv, r[2 + 2 + kx], a2);
                a3 = fmaf(wv, r[2 + 3 + kx], a3);
            }
        }
        d[c][0] = a0; d[c][1] = a1; d[c][2] = a2; d[c][3] = a3;
    }

    float* __restrict__ dst = agg + ((size_t)b * 768 + 8 * p) * NPIX + (y0 + ty) * 64 + x0;
#pragma unroll
    for (int o = 0; o < 8; ++o) {
        const float* __restrict__ wo = w_pw + (size_t)(8 * p + o) * 8;
        float4 s = {0.f, 0.f, 0.f, 0.f};
#pragma unroll
        for (int i = 0; i < 8; ++i) {
            const float wv = wo[i];
            s.x = fmaf(wv, d[i][0], s.x);
            s.y = fmaf(wv, d[i][1], s.y);
            s.z = fmaf(wv, d[i][2], s.z);
            s.w = fmaf(wv, d[i][3], s.w);
        }
        *(float4*)(dst + (size_t)o * NPIX) = s;
    }
}

// ---------------------------------------------------------------------------
// kv reduction. Unchanged. grid = (64, batch); block = 256
// ---------------------------------------------------------------------------
__global__ __launch_bounds__(256) void kv_reduce(
    const float* __restrict__ qkv, const float* __restrict__ agg,
    float* __restrict__ kvb)      // [batch][64][72]
{
    const int g = blockIdx.x, b = blockIdx.y;
    const float* __restrict__ src = (g < 32) ? qkv : agg;
    const float* __restrict__ base = src + ((size_t)b * 768 + 24 * (g & 31)) * NPIX;

    float acc[72];
#pragma unroll
    for (int i = 0; i < 72; ++i) acc[i] = 0.0f;

    for (int i4 = threadIdx.x; i4 < NPIX / 4; i4 += 256) {
        float4 kf[8], vf[8];
#pragma unroll
        for (int d = 0; d < 8; ++d) {
            float4 t = ((const float4*)(base + (size_t)(8 + d) * NPIX))[i4];
            kf[d].x = fmaxf(0.0f, t.x); kf[d].y = fmaxf(0.0f, t.y);
            kf[d].z = fmaxf(0.0f, t.z); kf[d].w = fmaxf(0.0f, t.w);
        }
#pragma unroll
        for (int e = 0; e < 8; ++e)
            vf[e] = ((const float4*)(base + (size_t)(16 + e) * NPIX))[i4];
#pragma unroll
        for (int d = 0; d < 8; ++d) {
#pragma unroll
            for (int e = 0; e < 8; ++e)
                acc[d * 9 + e] += kf[d].x * vf[e].x + kf[d].y * vf[e].y +
                                  kf[d].z * vf[e].z + kf[d].w * vf[e].w;
            acc[d * 9 + 8] += kf[d].x + kf[d].y + kf[d].z + kf[d].w;
        }
    }

    const int lane = threadIdx.x & 63;
    const int wv   = threadIdx.x >> 6;
#pragma unroll
    for (int i = 0; i < 72; ++i) {
        float v = acc[i];
        v += __shfl_xor(v, 32, 64);
        v += __shfl_xor(v, 16, 64);
        v += __shfl_xor(v, 8, 64);
        v += __shfl_xor(v, 4, 64);
        v += __shfl_xor(v, 2, 64);
        v += __shfl_xor(v, 1, 64);
        acc[i] = v;
    }
    __shared__ float red[4][72];
    if (lane == 0) {
#pragma unroll
        for (int i = 0; i < 72; ++i) red[wv][i] = acc[i];
    }
    __syncthreads();
    if (threadIdx.x < 72)
        kvb[((size_t)b * 64 + g) * 72 + threadIdx.x] =
            red[0][threadIdx.x] + red[1][threadIdx.x] +
            red[2][threadIdx.x] + red[3][threadIdx.x];
}

// ---------------------------------------------------------------------------
// attn_fused. Unchanged. grid = (128, 8); block = 256
// ---------------------------------------------------------------------------
__global__ __launch_bounds__(256) void attn_fused(
    const float* __restrict__ qkv, const float* __restrict__ agg,
    const float* __restrict__ kvb,   // [batch][64][72]
    bf16* __restrict__ attTh, bf16* __restrict__ attTm)  // [8][NPIX][512]
{
    const int b   = blockIdx.y;
    const int n0  = blockIdx.x * 32;
    const int tid = threadIdx.x;
    const int p   = tid & 31;
    const int c   = tid >> 5;

    __shared__ float kvs[64 * 72];
    for (int i = tid; i < 64 * 72; i += 256) kvs[i] = kvb[(size_t)b * 64 * 72 + i];
    __syncthreads();

    const int n = n0 + p;
    const size_t orow = ((size_t)b * NPIX + n) * 512;

#pragma unroll
    for (int gi = 0; gi < 8; ++gi) {
        const int g = c * 8 + gi;
        const float* __restrict__ src = (g < 32) ? qkv : agg;
        const float* __restrict__ base = src + ((size_t)b * 768 + 24 * (g & 31)) * NPIX + n;

        float q[8];
#pragma unroll
        for (int d = 0; d < 8; ++d) q[d] = fmaxf(0.0f, base[(size_t)d * NPIX]);

        const float* kv = &kvs[g * 72];
        float den = 1e-15f;
#pragma unroll
        for (int d = 0; d < 8; ++d) den = fmaf(q[d], kv[d * 9 + 8], den);
        float inv = 1.0f / den;
#pragma unroll
        for (int d = 0; d < 8; ++d) q[d] *= inv;

        bf16x8 vh, vm;
#pragma unroll
        for (int e = 0; e < 8; ++e) {
            float o = 0.0f;
#pragma unroll
            for (int d = 0; d < 8; ++d) o = fmaf(q[d], kv[d * 9 + e], o);
            bf16 h = (bf16)o;
            vh[e] = h;
            vm[e] = (bf16)(o - (float)h);
        }
        *(bf16x8*)(attTh + orow + g * 8) = vh;
        *(bf16x8*)(attTm + orow + g * 8) = vm;
    }
}

// ---------------------------------------------------------------------------
// proj GEMM via split-2 bf16 MFMA + fused BN.
// v4: B register prefetch one K-step ahead; plain __syncthreads() per step.
// grid = (32, 2, 8); block = 256
// ---------------------------------------------------------------------------
__global__ __launch_bounds__(256, 2) void proj_mfma(
    const bf16* __restrict__ Ph, const bf16* __restrict__ Pm,  // [256][512]
    const bf16* __restrict__ Bh, const bf16* __restrict__ Bm,  // [8][NPIX][512]
    float* __restrict__ C,           // [8][256][NPIX]
    const float* __restrict__ bn_g, const float* __restrict__ bn_b,
    const float* __restrict__ bn_m, const float* __restrict__ bn_v)
{
    __shared__ __align__(16) bf16 As[2][2][128][32];   // 32 KiB

    const int tid  = threadIdx.x;
    const int lane = tid & 63;
    const int wv   = tid >> 6;
    const int col  = lane & 15;
    const int quad = lane >> 4;
    const int wm   = (wv >> 1) * 64;
    const int wn   = (wv & 1) * 64;
    const int n0   = blockIdx.x * 128;
    const int m0   = blockIdx.y * 128;
    const int b    = blockIdx.z;

    const size_t boff = ((size_t)b * NPIX + n0 + wn) * 512;

    const int srow = wv * 16 + (lane >> 2);
    const int schk = (lane & 3) * 8;

    const bf16* AP[2] = {Ph, Pm};

    auto stage = [&](int buf, int kk) {
#pragma unroll
        for (int p = 0; p < 2; ++p)
#pragma unroll
            for (int hh = 0; hh < 2; ++hh) {
                const bf16* gp = AP[p] + (size_t)(m0 + hh * 64 + srow) * 512 + kk + schk;
                __builtin_amdgcn_global_load_lds(
                    (const __attribute__((address_space(1))) void*)gp,
                    (__attribute__((address_space(3))) void*)&As[buf][p][hh * 64 + wv * 16][0],
                    16, 0, 0);
            }
    };

    f32x4 acc[4][4] = {};

    stage(0, 0);
    bf16x8 bh[4], bm2[4];
#pragma unroll
    for (int t = 0; t < 4; ++t) {
        const size_t brow = boff + (size_t)(t * 16 + col) * 512 + 0 + quad * 8;
        bh[t]  = *(const bf16x8*)(Bh + brow);
        bm2[t] = *(const bf16x8*)(Bm + brow);
    }

#pragma unroll
    for (int k0 = 0; k0 < 512; k0 += 32) {
        const int cur = (k0 >> 5) & 1;
        const bool more = (k0 + 32 < 512);

        __syncthreads();

        bf16x8 af0[4], af1[4];
#pragma unroll
        for (int s = 0; s < 4; ++s) {
            af0[s] = *(const bf16x8*)&As[cur][0][wm + s * 16 + col][quad * 8];
            af1[s] = *(const bf16x8*)&As[cur][1][wm + s * 16 + col][quad * 8];
        }

        bf16x8 nbh[4], nbm[4];
        if (more) {
            stage(cur ^ 1, k0 + 32);
#pragma unroll
            for (int t = 0; t < 4; ++t) {
                const size_t brow = boff + (size_t)(t * 16 + col) * 512 + (k0 + 32) + quad * 8;
                nbh[t] = *(const bf16x8*)(Bh + brow);
                nbm[t] = *(const bf16x8*)(Bm + brow);
            }
        }

#pragma unroll
        for (int t = 0; t < 4; ++t)
#pragma unroll
            for (int s = 0; s < 4; ++s)
                acc[s][t] = __builtin_amdgcn_mfma_f32_16x16x32_bf16(af1[s], bh[t], acc[s][t], 0, 0, 0);
#pragma unroll
        for (int t = 0; t < 4; ++t)
#pragma unroll
            for (int s = 0; s < 4; ++s)
                acc[s][t] = __builtin_amdgcn_mfma_f32_16x16x32_bf16(af0[s], bm2[t], acc[s][t], 0, 0, 0);
#pragma unroll
        for (int t = 0; t < 4; ++t)
#pragma unroll
            for (int s = 0; s < 4; ++s)
                acc[s][t] = __builtin_amdgcn_mfma_f32_16x16x32_bf16(af0[s], bh[t], acc[s][t], 0, 0, 0);

        if (more) {
#pragma unroll
            for (int t = 0; t < 4; ++t) {
                bh[t] = nbh[t]; bm2[t] = nbm[t];
            }
        }
    }

    float* __restrict__ Cp = C + (size_t)b * 256 * NPIX;
#pragma unroll
    for (int s = 0; s < 4; ++s) {
#pragma unroll
        for (int r = 0; r < 4; ++r) {
            const int m = m0 + wm + s * 16 + quad * 4 + r;
            const float sc  = (1.0f / sqrtf(bn_v[m] + 1e-5f)) * bn_g[m];
            const float off = bn_b[m] - bn_m[m] * sc;
#pragma unroll
            for (int t = 0; t < 4; ++t) {
                const int n = n0 + wn + t * 16 + col;
                Cp[(size_t)m * NPIX + n] = acc[s][t][r] * sc + off;
            }
        }
    }
}

// ---------------------------------------------------------------------------
extern "C" void kernel_launch(void* const* d_in, const int* in_sizes, int n_in,
                              void* d_out, int out_size, void* d_ws, size_t ws_size,
                              hipStream_t stream) {
    const float* x      = (const float*)d_in[0];
    const float* w_qkv  = (const float*)d_in[1];
    const float* w_dw   = (const float*)d_in[2];
    const float* w_pw   = (const float*)d_in[3];
    const float* w_proj = (const float*)d_in[4];
    const float* bn_g   = (const float*)d_in[5];
    const float* bn_b   = (const float*)d_in[6];
    const float* bn_m   = (const float*)d_in[7];
    const float* bn_v   = (const float*)d_in[8];
    float* out = (float*)d_out;

    // ws: qkv 96 MiB + agg 96 MiB + region3 64 MiB = 256 MiB.
    // region3: xT planes (48 MiB) + wq planes (1.2 MiB at +48Mi) until
    //          qkv_mfma done, then attT h+m (2 x 32 MiB) overwrite it.
    // wp planes (0.5 MiB) go into the qkv region AFTER attn_fused (qkv dead).
    // kvb (147 KB) lives in d_out; proj_mfma overwrites all of d_out last.
    char* ws = (char*)d_ws;
    float* qkv  = (float*)ws;                        // 100663296 B
    float* agg  = (float*)(ws + 100663296ull);       // 100663296 B
    char*  r3   = ws + 201326592ull;                 // 67108864 B
    bf16*  xTh  = (bf16*)r3;                         // 16777216 B
    bf16*  xTm  = (bf16*)(r3 + 16777216ull);         // 16777216 B
    bf16*  xTl  = (bf16*)(r3 + 33554432ull);         // 16777216 B
    bf16*  wqh  = (bf16*)(r3 + 50331648ull);         // 393216 B
    bf16*  wqm  = (bf16*)(r3 + 50331648ull + 393216ull);
    bf16*  wql  = (bf16*)(r3 + 50331648ull + 786432ull);
    bf16*  attTh = (bf16*)r3;                        // 33554432 B
    bf16*  attTm = (bf16*)(r3 + 33554432ull);        // 33554432 B
    bf16*  wph  = (bf16*)ws;                         // 262144 B (qkv dead)
    bf16*  wpm  = (bf16*)(ws + 262144ull);           // 262144 B
    float* kvb  = (float*)d_out;

    // 0) split + transpose x into 3 bf16 planes (h+m+l == x exactly)
    split_x<<<dim3(16, 8, 8), dim3(256), 0, stream>>>(x, xTh, xTm, xTl);

    // 0b) split w_qkv into 3 bf16 planes
    split_w3<<<dim3(768), dim3(256), 0, stream>>>(w_qkv, wqh, wqm, wql);

    // 1) qkv = w_qkv @ x  (split-3 MFMA, fp32-accurate)
    qkv_mfma<<<dim3(32, 6, 8), dim3(256), 0, stream>>>(
        wqh, wqm, wql, xTh, xTm, xTl, qkv);

    // 2) agg = grouped-pw( depthwise-5x5( qkv ) )
    dwpw<<<dim3(4, 96, 8), dim3(256), 0, stream>>>(qkv, w_dw, w_pw, agg);

    // 3) kv reduction per (g, b)
    kv_reduce<<<dim3(64, 8), dim3(256), 0, stream>>>(qkv, agg, kvb);

    // 4) attention -> transposed split-2 bf16 attT (xT + wq region now dead)
    attn_fused<<<dim3(128, 8), dim3(256), 0, stream>>>(qkv, agg, kvb, attTh, attTm);

    // 4b) split w_proj into 2 bf16 planes -> qkv region (dead after attn_fused)
    split_w2<<<dim3(512), dim3(256), 0, stream>>>(w_proj, wph, wpm);

    // 5) out = BN( w_proj @ att )  (split-2 MFMA; overwrites all of d_out)
    proj_mfma<<<dim3(32, 2, 8), dim3(256), 0, stream>>>(
        wph, wpm, attTh, attTm, out, bn_g, bn_b, bn_m, bn_v);
}